// Round 10
// baseline (1518.275 us; speedup 1.0000x reference)
//
#include <hip/hip_runtime.h>
#include <math.h>

#define H 128
#define NTX 150000
#define NCU 40000
#define NME 10000
#define NEDGE 150000
#define NLAY 2
#define WC_STRIDE 33280     // per (l,r): QWc@0, WVc@16384, qbc@32768, bvc@32896
#define WKC_STRIDE 16640    // per (l,r): WKc@0
#define BUF_FLOATS 19200000       // NTX*H (edgebuf and bufB each)
#define AGG2_OFF 5120000          // bufB offset for agg[2] region (after NCU*H)
#define SCAN_TILE 2048

typedef short s8v __attribute__((ext_vector_type(8)));
typedef float f32x4 __attribute__((ext_vector_type(4)));

__device__ __forceinline__ float gelu_exact(float x) {
    return 0.5f * x * (1.0f + erff(x * 0.70710678118654752f));
}
__device__ __forceinline__ unsigned short f2bf(float x) {   // RNE f32->bf16 bits
    unsigned u = __float_as_uint(x);
    return (unsigned short)((u + 0x7FFFu + ((u >> 16) & 1u)) >> 16);
}
__device__ __forceinline__ float bf2f(unsigned short b) {
    return __uint_as_float(((unsigned)b) << 16);
}

// ---------- fills ----------
__global__ __launch_bounds__(256) void fill_val(float* p, int n, float v) {
    int i = blockIdx.x * 256 + threadIdx.x;
    if (i < n) p[i] = v;
}
__global__ __launch_bounds__(256) void zero_int(int* p, int n) {
    int i = blockIdx.x * 256 + threadIdx.x;
    if (i < n) p[i] = 0;
}
__global__ __launch_bounds__(256) void copy_int(int* d, const int* s, int n) {
    int i = blockIdx.x * 256 + threadIdx.x;
    if (i < n) d[i] = s[i];
}

// ---------- CSR build ----------
__global__ __launch_bounds__(256) void count_deg(const int* __restrict__ dst,
    int* __restrict__ deg, int E)
{
    int e = blockIdx.x * 256 + threadIdx.x;
    if (e < E) atomicAdd(&deg[dst[e]], 1);
}
__global__ __launch_bounds__(256) void scan1(const int* __restrict__ deg,
    int* __restrict__ out, int* __restrict__ bsum, int n)
{
    __shared__ int ts[256];
    int tid = threadIdx.x;
    int base = blockIdx.x * SCAN_TILE + tid * 8;
    int v[8], pre[8], s = 0;
    #pragma unroll
    for (int j = 0; j < 8; ++j) {
        int idx = base + j;
        v[j] = (idx < n) ? deg[idx] : 0;
        pre[j] = s; s += v[j];
    }
    ts[tid] = s;
    __syncthreads();
    for (int off = 1; off < 256; off <<= 1) {
        int t = (tid >= off) ? ts[tid - off] : 0;
        __syncthreads();
        ts[tid] += t;
        __syncthreads();
    }
    int excl = ts[tid] - s;
    #pragma unroll
    for (int j = 0; j < 8; ++j)
        if (base + j < n) out[base + j] = excl + pre[j];
    if (tid == 255) bsum[blockIdx.x] = ts[255];
}
__global__ __launch_bounds__(64) void scan2(int* __restrict__ bsum, int nb) {
    if (threadIdx.x == 0 && blockIdx.x == 0) {
        int run = 0;
        for (int i = 0; i < nb; ++i) { int t = bsum[i]; bsum[i] = run; run += t; }
    }
}
__global__ __launch_bounds__(256) void scan3(int* __restrict__ out,
    const int* __restrict__ bsum, int n, int total)
{
    int base = blockIdx.x * SCAN_TILE;
    int add = bsum[blockIdx.x];
    for (int j = threadIdx.x; j < SCAN_TILE; j += 256) {
        int k = base + j;
        if (k < n) out[k] += add;
    }
    if (blockIdx.x == 0 && threadIdx.x == 0) out[n] = total;
}
__global__ __launch_bounds__(256) void fill_csr(const int* __restrict__ src,
    const int* __restrict__ dst, int* __restrict__ cursor, int* __restrict__ col, int E)
{
    int e = blockIdx.x * 256 + threadIdx.x;
    if (e >= E) return;
    int pos = atomicAdd(&cursor[dst[e]], 1);
    col[pos] = src[e];
}

// ---------- vectorized projection: Y = X(NxK) @ W(KxH) + b, 8 nodes/block ----------
template<int K>
__global__ __launch_bounds__(256) void proj_kernel(const float* __restrict__ X,
    const float* __restrict__ W, const float* __restrict__ B,
    float* __restrict__ Y, int N)
{
    __shared__ float Wl[K][128];
    __shared__ float Bl[128];
    int tid = threadIdx.x;
    for (int i = tid; i < K * 128; i += 256) Wl[i >> 7][i & 127] = W[i];
    if (tid < 128) Bl[tid] = B[tid];
    __syncthreads();
    int ng = tid >> 5, lane = tid & 31;
    int n = blockIdx.x * 8 + ng;
    if (n >= N) return;
    const float* xr = X + (size_t)n * K;
    float xa[K];
    #pragma unroll
    for (int k4 = 0; k4 < K / 4; ++k4)
        *(float4*)&xa[k4 * 4] = *(const float4*)(xr + k4 * 4);
    int c0 = lane * 4;
    float4 acc = *(const float4*)&Bl[c0];
    #pragma unroll
    for (int k = 0; k < K; ++k) {
        float4 w = *(const float4*)&Wl[k][c0];
        acc.x += xa[k] * w.x; acc.y += xa[k] * w.y;
        acc.z += xa[k] * w.z; acc.w += xa[k] * w.w;
    }
    *(float4*)(Y + (size_t)n * H + c0) = acc;
}

// ---------- gather rows ----------
__global__ __launch_bounds__(256) void gather_rows(const float* __restrict__ src,
    const int* __restrict__ ids, float* __restrict__ dstp, int N)
{
    int t = blockIdx.x * 256 + threadIdx.x;
    if (t >= N * 32) return;
    int n = t >> 5, c4 = t & 31;
    int sid = ids[n];
    ((float4*)dstp)[(size_t)n * 32 + c4] = ((const float4*)src)[(size_t)sid * 32 + c4];
}

// ---------- combine stage 1 (parallel, 64 blocks) ----------
__global__ __launch_bounds__(256) void combine1_par(const float* __restrict__ kw,
    const float* __restrict__ kb, const float* __restrict__ vw, const float* __restrict__ vb,
    const float* __restrict__ a_rel, const float* __restrict__ m_rel,
    float* __restrict__ wkc, float* __restrict__ wc)
{
    __shared__ float Rs[64][132];
    int b = blockIdx.x;
    int combo = b >> 3;
    int pass  = (b >> 2) & 1;
    int slice = b & 3;
    int l = combo >> 2, r = combo & 3;
    const int src_t[4] = {1, 2, 0, 0};
    int st = src_t[r];
    const float* Ap = (pass ? vw : kw) + (size_t)(l*3 + st) * H * H;
    const float* Rp = (pass ? m_rel : a_rel) + (size_t)combo * H * H;
    float* Out = pass ? (wc + (size_t)combo * WC_STRIDE + 16384)
                      : (wkc + (size_t)combo * WKC_STRIDE);

    int tid = threadIdx.x;
    int i = slice * 32 + (tid >> 3);
    int jb = tid & 7;
    float acc[16];
    #pragma unroll
    for (int j = 0; j < 16; ++j) acc[j] = 0.f;

    for (int half = 0; half < 2; ++half) {
        __syncthreads();
        for (int idx = tid; idx < 64 * 128; idx += 256)
            Rs[idx >> 7][idx & 127] = Rp[(half * 64 + (idx >> 7)) * H + (idx & 127)];
        __syncthreads();
        for (int k = 0; k < 64; ++k) {
            float a = Ap[i * H + half * 64 + k];
            #pragma unroll
            for (int j = 0; j < 16; ++j) acc[j] += a * Rs[k][jb + j * 8];
        }
    }
    #pragma unroll
    for (int j = 0; j < 16; ++j) Out[i * H + jb + j * 8] = acc[j];

    // bvc = vb @ m_rel  (cvec/bkc terms cancel in segment softmax -> not computed)
    if (pass == 0 && slice == 0 && tid < 128) {
        const float* Avb = vb + (size_t)(l*3 + st) * H;
        const float* Rv = m_rel + (size_t)combo * H * H;
        float* bvc = wc + (size_t)combo * WC_STRIDE + 32896;
        float s = 0.f;
        for (int k = 0; k < H; ++k) s += Avb[k] * Rv[k * H + tid];
        bvc[tid] = s;
    }
}

// ---------- combine stage 2 (parallel, 32 blocks): QWc = qw[dt] @ WKc^T ----------
__global__ __launch_bounds__(256) void combine2_par(const float* __restrict__ qw,
    const float* __restrict__ qb, const float* __restrict__ wkc, float* __restrict__ wc)
{
    __shared__ float BsT[64][133];
    int b = blockIdx.x;
    int combo = b >> 2;
    int slice = b & 3;
    int l = combo >> 2, r = combo & 3;
    const int dst_t[4] = {0, 0, 1, 2};
    int dt = dst_t[r];
    const float* Q  = qw + (size_t)(l*3 + dt) * H * H;
    const float* Qb = qb + (size_t)(l*3 + dt) * H;
    const float* WKc = wkc + (size_t)combo * WKC_STRIDE;
    float* QWc = wc + (size_t)combo * WC_STRIDE;

    int tid = threadIdx.x;
    int i = slice * 32 + (tid >> 3);
    int jb = tid & 7;
    float acc[16];
    #pragma unroll
    for (int j = 0; j < 16; ++j) acc[j] = 0.f;

    for (int half = 0; half < 2; ++half) {
        __syncthreads();
        for (int idx = tid; idx < 64 * 128; idx += 256) {
            int j = idx >> 6, k = idx & 63;
            BsT[k][j] = WKc[j * H + half * 64 + k];
        }
        __syncthreads();
        for (int k = 0; k < 64; ++k) {
            float a = Q[i * H + half * 64 + k];
            #pragma unroll
            for (int j = 0; j < 16; ++j) acc[j] += a * BsT[k][jb + j * 8];
        }
    }
    #pragma unroll
    for (int j = 0; j < 16; ++j) QWc[i * H + jb + j * 8] = acc[j];

    if (slice == 0 && tid < 128) {
        float* qbc = wc + (size_t)combo * WC_STRIDE + 32768;
        float s = 0.f;
        for (int k = 0; k < H; ++k) s += Qb[k] * WKc[tid * H + k];
        qbc[tid] = s;
    }
}

// ---------- weight prep: transpose + split f32 -> bf16 hi/lo, layout [j][k] ----------
__global__ __launch_bounds__(256) void wprep(const float* __restrict__ wc,
    const float* __restrict__ aw, unsigned short* __restrict__ wt)
{
    int b = blockIdx.x;
    const float* src = (b < 16)
        ? wc + (size_t)(b >> 1) * WC_STRIDE + ((b & 1) ? 16384 : 0)
        : aw + (size_t)(b - 16) * 16384;
    unsigned short* hi = wt + (size_t)b * 32768;
    unsigned short* lo = hi + 16384;
    for (int idx = threadIdx.x; idx < 16384; idx += 256) {
        int k = idx >> 7, j = idx & 127;
        float w = src[idx];
        unsigned short h = f2bf(w);
        hi[j * 128 + k] = h;
        lo[j * 128 + k] = f2bf(w - bf2f(h));
    }
}

// ---------- 32-row tile GEMM machinery (16 KB LDS, low VGPR) ----------
// LDS [2][32][128] ushort, XOR-swizzled (col ^ ((row&7)<<3))
#define STAGE32(SRC, GELU)                                                  \
    _Pragma("unroll")                                                       \
    for (int i = 0; i < 4; ++i) {                                           \
        int u = tid + i * 256;                                              \
        int n = u >> 5, c4 = u & 31;                                        \
        int gn = nb + n;                                                    \
        float4 v = make_float4(0.f, 0.f, 0.f, 0.f);                         \
        if (gn < N) v = *(const float4*)((SRC) + (size_t)gn * H + c4 * 4);  \
        if (GELU) {                                                         \
            v.x = gelu_exact(v.x); v.y = gelu_exact(v.y);                   \
            v.z = gelu_exact(v.z); v.w = gelu_exact(v.w);                   \
        }                                                                   \
        ushort4 h, lo;                                                      \
        h.x = f2bf(v.x); lo.x = f2bf(v.x - bf2f(h.x));                      \
        h.y = f2bf(v.y); lo.y = f2bf(v.y - bf2f(h.y));                      \
        h.z = f2bf(v.z); lo.z = f2bf(v.z - bf2f(h.z));                      \
        h.w = f2bf(v.w); lo.w = f2bf(v.w - bf2f(h.w));                      \
        int sc = (c4 * 4) ^ ((n & 7) << 3);                                 \
        *(ushort4*)&lds[0][n][sc] = h;                                      \
        *(ushort4*)&lds[1][n][sc] = lo;                                     \
    }

#define CVT32(REG)                                                          \
    _Pragma("unroll")                                                       \
    for (int i = 0; i < 4; ++i) {                                           \
        int u = tid + i * 256;                                              \
        int n = u >> 5, c4 = u & 31;                                        \
        float4 v = REG[i];                                                  \
        ushort4 h, lo;                                                      \
        h.x = f2bf(v.x); lo.x = f2bf(v.x - bf2f(h.x));                      \
        h.y = f2bf(v.y); lo.y = f2bf(v.y - bf2f(h.y));                      \
        h.z = f2bf(v.z); lo.z = f2bf(v.z - bf2f(h.z));                      \
        h.w = f2bf(v.w); lo.w = f2bf(v.w - bf2f(h.w));                      \
        int sc = (c4 * 4) ^ ((n & 7) << 3);                                 \
        *(ushort4*)&lds[0][n][sc] = h;                                      \
        *(ushort4*)&lds[1][n][sc] = lo;                                     \
    }

// weights loaded per-kb (4 s8v live instead of 16): low register pressure
#define MFMA_TILE(WT)                                                       \
    _Pragma("unroll")                                                       \
    for (int kb = 0; kb < 4; ++kb) {                                        \
        const unsigned short* wp = (WT) + kb * 32 + kg * 8;                 \
        s8v bh0 = *(const s8v*)(wp + (size_t)(col0 + l15) * 128);           \
        s8v bh1 = *(const s8v*)(wp + (size_t)(col0 + 16 + l15) * 128);      \
        s8v bl0 = *(const s8v*)(wp + 16384 + (size_t)(col0 + l15) * 128);   \
        s8v bl1 = *(const s8v*)(wp + 16384 + (size_t)(col0 + 16 + l15) * 128); \
        _Pragma("unroll")                                                   \
        for (int m = 0; m < 2; ++m) {                                       \
            int row = m * 16 + l15;                                         \
            int offx = (kb * 32 + kg * 8) ^ ((row & 7) << 3);               \
            s8v ah = *(const s8v*)&lds[0][row][offx];                       \
            s8v al = *(const s8v*)&lds[1][row][offx];                       \
            acc[m][0] = __builtin_amdgcn_mfma_f32_16x16x32_bf16(ah, bh0, acc[m][0], 0, 0, 0); \
            acc[m][0] = __builtin_amdgcn_mfma_f32_16x16x32_bf16(al, bh0, acc[m][0], 0, 0, 0); \
            acc[m][0] = __builtin_amdgcn_mfma_f32_16x16x32_bf16(ah, bl0, acc[m][0], 0, 0, 0); \
            acc[m][1] = __builtin_amdgcn_mfma_f32_16x16x32_bf16(ah, bh1, acc[m][1], 0, 0, 0); \
            acc[m][1] = __builtin_amdgcn_mfma_f32_16x16x32_bf16(al, bh1, acc[m][1], 0, 0, 0); \
            acc[m][1] = __builtin_amdgcn_mfma_f32_16x16x32_bf16(ah, bl1, acc[m][1], 0, 0, 0); \
        }                                                                   \
    }

// ---------- MFMA split-bf16 GEMM (single weight set), 32 rows/block ----------
// MODE 0: Y = X@W + B
// MODE 1: Y = relu(beta*(gelu(X)@W + B) + (1-beta)*Xold)
// MODE 3: Y = X@W + gate*B    (gate = zb[n]>0; X==Y in-place allowed)
template<int MODE>
__global__ __launch_bounds__(256, 8) void mfma_gemm(const float* __restrict__ X,
    const unsigned short* __restrict__ Wt, const float* __restrict__ Bias,
    float* __restrict__ Y, int N, const float* __restrict__ Xold,
    const float* __restrict__ skipP, const float* __restrict__ zb)
{
    __shared__ unsigned short lds[2][32][128];
    int tid = threadIdx.x;
    int nb = blockIdx.x * 32;

    STAGE32(X, MODE == 1)
    __syncthreads();

    int wid = tid >> 6, lane = tid & 63;
    int l15 = lane & 15, kg = lane >> 4;
    int col0 = wid * 32;

    f32x4 acc[2][2];
    #pragma unroll
    for (int m = 0; m < 2; ++m)
        #pragma unroll
        for (int n = 0; n < 2; ++n)
            acc[m][n] = (f32x4){0.f, 0.f, 0.f, 0.f};

    MFMA_TILE(Wt)

    float beta = 0.f, omb = 0.f;
    if (MODE == 1) {
        float s = *skipP;
        beta = 1.f / (1.f + expf(-s));
        omb = 1.f - beta;
    }
    float bias0 = Bias[col0 + l15];
    float bias1 = Bias[col0 + 16 + l15];

    #pragma unroll
    for (int m = 0; m < 2; ++m) {
        #pragma unroll
        for (int r = 0; r < 4; ++r) {
            int grow = nb + m * 16 + kg * 4 + r;
            if (grow < N) {
                float gate = 1.f;
                if (MODE == 3) gate = (zb[grow] > 0.f) ? 1.f : 0.f;
                #pragma unroll
                for (int n = 0; n < 2; ++n) {
                    int col = col0 + n * 16 + l15;
                    float val = acc[m][n][r];
                    float bs = n ? bias1 : bias0;
                    size_t yi = (size_t)grow * H + col;
                    if (MODE == 0) {
                        Y[yi] = val + bs;
                    } else if (MODE == 3) {
                        Y[yi] = val + gate * bs;
                    } else {
                        float o = val + bs;
                        float xo = Xold[yi];
                        Y[yi] = fmaxf(beta * o + omb * xo, 0.f);
                    }
                }
            }
        }
    }
}

// ---------- fused dual qt GEMM: Y0 = X@W0 + b0, Y1 = X@W1 + b1 ----------
__global__ __launch_bounds__(256, 8) void mfma_gemm2q(const float* __restrict__ X,
    const unsigned short* __restrict__ Wt0, const unsigned short* __restrict__ Wt1,
    const float* __restrict__ b0, const float* __restrict__ b1,
    float* __restrict__ Y0, float* __restrict__ Y1, int N)
{
    __shared__ unsigned short lds[2][32][128];
    int tid = threadIdx.x;
    int nb = blockIdx.x * 32;

    STAGE32(X, 0)
    __syncthreads();

    int wid = tid >> 6, lane = tid & 63;
    int l15 = lane & 15, kg = lane >> 4;
    int col0 = wid * 32;

    #pragma unroll
    for (int set = 0; set < 2; ++set) {
        const unsigned short* Wt = set ? Wt1 : Wt0;
        const float* Bias = set ? b1 : b0;
        float* Y = set ? Y1 : Y0;

        f32x4 acc[2][2];
        #pragma unroll
        for (int m = 0; m < 2; ++m)
            #pragma unroll
            for (int n = 0; n < 2; ++n)
                acc[m][n] = (f32x4){0.f, 0.f, 0.f, 0.f};

        MFMA_TILE(Wt)

        float bias0 = Bias[col0 + l15];
        float bias1 = Bias[col0 + 16 + l15];
        #pragma unroll
        for (int m = 0; m < 2; ++m) {
            #pragma unroll
            for (int r = 0; r < 4; ++r) {
                int grow = nb + m * 16 + kg * 4 + r;
                if (grow < N) {
                    #pragma unroll
                    for (int n = 0; n < 2; ++n) {
                        int col = col0 + n * 16 + l15;
                        Y[(size_t)grow * H + col] = acc[m][n][r] + (n ? bias1 : bias0);
                    }
                }
            }
        }
    }
}

// ---------- fused K=256 V-GEMM: A0 <- A0@W0 + A1@W1 + gate0*b0 + gate1*b1 ----------
__global__ __launch_bounds__(256, 6) void mfma_gemmV2(float* __restrict__ A0,
    const float* __restrict__ A1,
    const unsigned short* __restrict__ Wt0, const unsigned short* __restrict__ Wt1,
    const float* __restrict__ bv0, const float* __restrict__ bv1,
    const float* __restrict__ z0, const float* __restrict__ z1, int N)
{
    __shared__ unsigned short lds[2][32][128];
    int tid = threadIdx.x;
    int nb = blockIdx.x * 32;
    int wid = tid >> 6, lane = tid & 63;
    int l15 = lane & 15, kg = lane >> 4;
    int col0 = wid * 32;

    // prefetch both input tiles (A1 latency hides under A0's MFMA pass)
    float4 ra[4], rb[4];
    #pragma unroll
    for (int i = 0; i < 4; ++i) {
        int u = tid + i * 256;
        int n = u >> 5, c4 = u & 31;
        int gn = nb + n;
        ra[i] = make_float4(0.f, 0.f, 0.f, 0.f);
        if (gn < N) ra[i] = *(const float4*)(A0 + (size_t)gn * H + c4 * 4);
    }
    #pragma unroll
    for (int i = 0; i < 4; ++i) {
        int u = tid + i * 256;
        int n = u >> 5, c4 = u & 31;
        int gn = nb + n;
        rb[i] = make_float4(0.f, 0.f, 0.f, 0.f);
        if (gn < N) rb[i] = *(const float4*)(A1 + (size_t)gn * H + c4 * 4);
    }

    f32x4 acc[2][2];
    #pragma unroll
    for (int m = 0; m < 2; ++m)
        #pragma unroll
        for (int n = 0; n < 2; ++n)
            acc[m][n] = (f32x4){0.f, 0.f, 0.f, 0.f};

    CVT32(ra)
    __syncthreads();
    MFMA_TILE(Wt0)
    __syncthreads();
    CVT32(rb)
    __syncthreads();
    MFMA_TILE(Wt1)

    float b00 = bv0[col0 + l15],  b01 = bv0[col0 + 16 + l15];
    float b10 = bv1[col0 + l15],  b11 = bv1[col0 + 16 + l15];

    #pragma unroll
    for (int m = 0; m < 2; ++m) {
        #pragma unroll
        for (int r = 0; r < 4; ++r) {
            int grow = nb + m * 16 + kg * 4 + r;
            if (grow < N) {
                float g0 = (z0[grow] > 0.f) ? 1.f : 0.f;
                float g1 = (z1[grow] > 0.f) ? 1.f : 0.f;
                #pragma unroll
                for (int n = 0; n < 2; ++n) {
                    int col = col0 + n * 16 + l15;
                    float bs = n ? (g0 * b01 + g1 * b11) : (g0 * b00 + g1 * b10);
                    A0[(size_t)grow * H + col] = acc[m][n][r] + bs;
                }
            }
        }
    }
}

// ---------- fused edge phase: per dst node, single pass over CSR ----------
__global__ __launch_bounds__(256) void gather_agg(const int* __restrict__ row_ptr,
    const int* __restrict__ col_idx, float* __restrict__ qtraw,
    const float* __restrict__ xsrc, const float* __restrict__ prel, int ridx,
    float* __restrict__ zout, int ndt)
{
    int g = blockIdx.x * 8 + (threadIdx.x >> 5);
    int lane = threadIdx.x & 31;
    if (g >= ndt) return;
    float4 qv = *(const float4*)(qtraw + (size_t)g * H + lane * 4);
    float scale = prel[ridx] * 0.08838834764831843f;   // 1/sqrt(128)
    int beg = row_ptr[g], end = row_ptr[g + 1];
    float4 acc = make_float4(0.f, 0.f, 0.f, 0.f);
    float z = 0.f;
    for (int i = beg; i < end; ++i) {
        int s = col_idx[i];
        float4 xv = *(const float4*)(xsrc + (size_t)s * H + lane * 4);
        float p = qv.x*xv.x + qv.y*xv.y + qv.z*xv.z + qv.w*xv.w;
        #pragma unroll
        for (int m = 16; m >= 1; m >>= 1) p += __shfl_xor(p, m);
        float ev = expf(p * scale);
        z += ev;
        acc.x += ev * xv.x; acc.y += ev * xv.y;
        acc.z += ev * xv.z; acc.w += ev * xv.w;
    }
    float inv = 1.f / (z + 1e-16f);
    float4 r = make_float4(acc.x * inv, acc.y * inv, acc.z * inv, acc.w * inv);
    *(float4*)(qtraw + (size_t)g * H + lane * 4) = r;
    if (lane == 0) zout[g] = z;
}

// ---------- output head ----------
__global__ __launch_bounds__(256) void out_kernel(const float* __restrict__ X,
    const float* __restrict__ Wo, const float* __restrict__ bo,
    float* __restrict__ out, int N)
{
    int t = blockIdx.x * 256 + threadIdx.x;
    int n = t >> 5, lane = t & 31;
    if (n >= N) return;
    float4 xv = *(const float4*)(X + (size_t)n * H + lane * 4);
    float xa[4]; *(float4*)xa = xv;
    float p0 = 0.f, p1 = 0.f;
    #pragma unroll
    for (int j = 0; j < 4; ++j) {
        p0 += xa[j] * Wo[(lane*4 + j)*2 + 0];
        p1 += xa[j] * Wo[(lane*4 + j)*2 + 1];
    }
    #pragma unroll
    for (int m = 16; m >= 1; m >>= 1) { p0 += __shfl_xor(p0, m); p1 += __shfl_xor(p1, m); }
    if (lane == 0) {
        out[(size_t)n*2 + 0] = p0 + bo[0];
        out[(size_t)n*2 + 1] = p1 + bo[1];
    }
}

extern "C" void kernel_launch(void* const* d_in, const int* in_sizes, int n_in,
                              void* d_out, int out_size, void* d_ws, size_t ws_size,
                              hipStream_t stream)
{
    const float* x_tx      = (const float*)d_in[0];
    const float* x_cust    = (const float*)d_in[1];
    const int*   merch_ids = (const int*)d_in[2];
    const int*   e_ct_src  = (const int*)d_in[3];
    const int*   e_ct_dst  = (const int*)d_in[4];
    const int*   e_mt_src  = (const int*)d_in[5];
    const int*   e_mt_dst  = (const int*)d_in[6];
    const float* proj_tx_w   = (const float*)d_in[7];
    const float* proj_tx_b   = (const float*)d_in[8];
    const float* proj_cust_w = (const float*)d_in[9];
    const float* proj_cust_b = (const float*)d_in[10];
    const float* merch_emb   = (const float*)d_in[11];
    const float* kw = (const float*)d_in[12];
    const float* kb = (const float*)d_in[13];
    const float* qw = (const float*)d_in[14];
    const float* qb = (const float*)d_in[15];
    const float* vw = (const float*)d_in[16];
    const float* vb = (const float*)d_in[17];
    const float* aw = (const float*)d_in[18];
    const float* ab = (const float*)d_in[19];
    const float* skip  = (const float*)d_in[20];
    const float* a_rel = (const float*)d_in[21];
    const float* m_rel = (const float*)d_in[22];
    const float* p_rel = (const float*)d_in[23];
    const float* out_w = (const float*)d_in[24];
    const float* out_b = (const float*)d_in[25];
    (void)in_sizes; (void)n_in;

    const size_t nsz[3] = {NTX, NCU, NME};

    // workspace layout — ~265 MB of 268.4 MB (256 MiB) budget
    float* ws = (float*)d_ws;
    size_t off = 0;
    float* xs[3];  for (int t = 0; t < 3; ++t) { xs[t] = ws + off; off += nsz[t]*H; }
    float* bufB    = ws + off; off += BUF_FLOATS;   // qt_r1/raw_r1; later agg1 @0, agg2 @AGG2_OFF
    float* edgebuf = ws + off; off += BUF_FLOATS;   // qt_r0/raw_r0 -> agg0 (in-place V2)
    float* zbuf0 = ws + off; off += NTX;
    float* zbuf1 = ws + off; off += NTX;
    float* wc   = ws + off; off += 8 * WC_STRIDE;
    float* wkc  = ws + off; off += 8 * WKC_STRIDE;
    int* ibase = (int*)(ws + off);
    const int rp_size[4] = {NTX + 1, NTX + 1, NCU + 1, NME + 1};
    int* rowp[4]; size_t ioff = 0;
    for (int r = 0; r < 4; ++r) { rowp[r] = ibase + ioff; ioff += rp_size[r]; }
    int* colix[4];
    for (int r = 0; r < 4; ++r) { colix[r] = ibase + ioff; ioff += NEDGE; }
    int* cursor = ibase + ioff; ioff += NTX;
    int* bsum   = ibase + ioff; ioff += 256;
    unsigned short* wt = (unsigned short*)(ibase + ioff);
    size_t needed_bytes = off * sizeof(float) + ioff * sizeof(int)
                        + (size_t)22 * 32768 * sizeof(unsigned short);

    if (ws_size < needed_bytes) {
        fill_val<<<(out_size + 255) / 256, 256, 0, stream>>>(
            (float*)d_out, out_size, (float)(ws_size >> 20));
        return;
    }

    const int src_t[4] = {1, 2, 0, 0};
    const int dst_t[4] = {0, 0, 1, 2};
    const int* esrc[4] = {e_ct_src, e_mt_src, e_ct_dst, e_mt_dst};
    const int* edst[4] = {e_ct_dst, e_mt_dst, e_ct_src, e_mt_src};

    // ---- build CSR per relation (edges constant across layers) ----
    const int egrid256 = (NEDGE + 255) / 256;
    for (int r = 0; r < 4; ++r) {
        int ndt = (int)nsz[dst_t[r]];
        int nb = (ndt + SCAN_TILE - 1) / SCAN_TILE;
        zero_int<<<(ndt + 255) / 256, 256, 0, stream>>>(cursor, ndt);
        count_deg<<<egrid256, 256, 0, stream>>>(edst[r], cursor, NEDGE);
        scan1<<<nb, 256, 0, stream>>>(cursor, rowp[r], bsum, ndt);
        scan2<<<1, 64, 0, stream>>>(bsum, nb);
        scan3<<<nb, 256, 0, stream>>>(rowp[r], bsum, ndt, NEDGE);
        copy_int<<<(ndt + 255) / 256, 256, 0, stream>>>(cursor, rowp[r], ndt);
        fill_csr<<<egrid256, 256, 0, stream>>>(esrc[r], edst[r], cursor, colix[r], NEDGE);
    }

    // precombine weights, then bf16 hi/lo transposed planes
    combine1_par<<<64, 256, 0, stream>>>(kw, kb, vw, vb, a_rel, m_rel, wkc, wc);
    combine2_par<<<32, 256, 0, stream>>>(qw, qb, wkc, wc);
    wprep<<<22, 256, 0, stream>>>(wc, aw, wt);

    // input projections
    proj_kernel<16><<<(NTX + 7) / 8, 256, 0, stream>>>(x_tx, proj_tx_w, proj_tx_b, xs[0], NTX);
    proj_kernel<32><<<(NCU + 7) / 8, 256, 0, stream>>>(x_cust, proj_cust_w, proj_cust_b, xs[1], NCU);
    gather_rows<<<(NME * 32 + 255) / 256, 256, 0, stream>>>(merch_emb, merch_ids, xs[2], NME);

    float* aggT[3] = { edgebuf, bufB, bufB + AGG2_OFF };

    for (int l = 0; l < NLAY; ++l) {
        int c0 = l * 4 + 0, c1 = l * 4 + 1;
        const float* W0 = wc + (size_t)c0 * WC_STRIDE;
        const float* W1 = wc + (size_t)c1 * WC_STRIDE;

        // fused r0+r1 qt (dt = tx for both): X read once
        mfma_gemm2q<<<(NTX + 31) / 32, 256, 0, stream>>>(
            xs[0], wt + (size_t)(c0*2) * 32768, wt + (size_t)(c1*2) * 32768,
            W0 + 32768, W1 + 32768, edgebuf, bufB, NTX);
        gather_agg<<<(NTX + 7) / 8, 256, 0, stream>>>(
            rowp[0], colix[0], edgebuf, xs[1], p_rel, c0, zbuf0, NTX);
        gather_agg<<<(NTX + 7) / 8, 256, 0, stream>>>(
            rowp[1], colix[1], bufB, xs[2], p_rel, c1, zbuf1, NTX);
        // agg0 = raw0@WV0 + raw1@WV1 (+ gated biases), in-place into edgebuf
        mfma_gemmV2<<<(NTX + 31) / 32, 256, 0, stream>>>(
            edgebuf, bufB, wt + (size_t)(c0*2 + 1) * 32768, wt + (size_t)(c1*2 + 1) * 32768,
            W0 + 32896, W1 + 32896, zbuf0, zbuf1, NTX);

        // r2 (dst=cust) and r3 (dst=merch): qt -> bufB regions, gather, V in-place
        for (int r = 2; r < 4; ++r) {
            int st = src_t[r], dt = dst_t[r];
            int ndt = (int)nsz[dt];
            int combo = l * 4 + r;
            const float* Wr = wc + (size_t)combo * WC_STRIDE;
            float* buf = aggT[dt];
            int grid = (ndt + 31) / 32;
            mfma_gemm<0><<<grid, 256, 0, stream>>>(
                xs[dt], wt + (size_t)(combo*2) * 32768, Wr + 32768, buf, ndt,
                nullptr, nullptr, nullptr);
            gather_agg<<<(ndt + 7) / 8, 256, 0, stream>>>(
                rowp[r], colix[r], buf, xs[st], p_rel, combo, zbuf0, ndt);
            mfma_gemm<3><<<grid, 256, 0, stream>>>(
                buf, wt + (size_t)(combo*2 + 1) * 32768, Wr + 32896, buf, ndt,
                nullptr, nullptr, zbuf0);
        }

        // update: xs = relu(beta*(gelu(agg)@aw + ab) + (1-beta)*xs)
        for (int t = 0; t < 3; ++t)
            mfma_gemm<1><<<(int)((nsz[t] + 31) / 32), 256, 0, stream>>>(
                aggT[t], wt + (size_t)(16 + l*3 + t) * 32768,
                ab + (size_t)(l*3 + t)*H, xs[t], (int)nsz[t],
                xs[t], skip + l*3 + t, nullptr);
    }

    out_kernel<<<(NTX * 32 + 255) / 256, 256, 0, stream>>>(xs[0], out_w, out_b, (float*)d_out, NTX);
}

// Round 11
// 1110.392 us; speedup vs baseline: 1.3673x; 1.3673x over previous
//
#include <hip/hip_runtime.h>
#include <math.h>

#define H 128
#define NTX 150000
#define NCU 40000
#define NME 10000
#define NEDGE 150000
#define NLAY 2
#define WC_STRIDE 33280     // per (l,r): QWc@0, WVc@16384, qbc@32768, bvc@32896
#define WKC_STRIDE 16640    // per (l,r): WKc@0
#define BUF_FLOATS 19200000       // NTX*H (edgebuf and bufB each)
#define AGG2_OFF 5120000          // bufB offset for agg[2] region (after NCU*H)
#define SCAN_TILE 2048

typedef short s8v __attribute__((ext_vector_type(8)));
typedef float f32x4 __attribute__((ext_vector_type(4)));

__device__ __forceinline__ float gelu_exact(float x) {
    return 0.5f * x * (1.0f + erff(x * 0.70710678118654752f));
}
__device__ __forceinline__ unsigned short f2bf(float x) {   // RNE f32->bf16 bits
    unsigned u = __float_as_uint(x);
    return (unsigned short)((u + 0x7FFFu + ((u >> 16) & 1u)) >> 16);
}
__device__ __forceinline__ float bf2f(unsigned short b) {
    return __uint_as_float(((unsigned)b) << 16);
}

// ---------- fills ----------
__global__ __launch_bounds__(256) void fill_val(float* p, int n, float v) {
    int i = blockIdx.x * 256 + threadIdx.x;
    if (i < n) p[i] = v;
}
__global__ __launch_bounds__(256) void zero_int(int* p, int n) {
    int i = blockIdx.x * 256 + threadIdx.x;
    if (i < n) p[i] = 0;
}
__global__ __launch_bounds__(256) void copy_int(int* d, const int* s, int n) {
    int i = blockIdx.x * 256 + threadIdx.x;
    if (i < n) d[i] = s[i];
}

// ---------- CSR build ----------
__global__ __launch_bounds__(256) void count_deg(const int* __restrict__ dst,
    int* __restrict__ deg, int E)
{
    int e = blockIdx.x * 256 + threadIdx.x;
    if (e < E) atomicAdd(&deg[dst[e]], 1);
}
__global__ __launch_bounds__(256) void scan1(const int* __restrict__ deg,
    int* __restrict__ out, int* __restrict__ bsum, int n)
{
    __shared__ int ts[256];
    int tid = threadIdx.x;
    int base = blockIdx.x * SCAN_TILE + tid * 8;
    int v[8], pre[8], s = 0;
    #pragma unroll
    for (int j = 0; j < 8; ++j) {
        int idx = base + j;
        v[j] = (idx < n) ? deg[idx] : 0;
        pre[j] = s; s += v[j];
    }
    ts[tid] = s;
    __syncthreads();
    for (int off = 1; off < 256; off <<= 1) {
        int t = (tid >= off) ? ts[tid - off] : 0;
        __syncthreads();
        ts[tid] += t;
        __syncthreads();
    }
    int excl = ts[tid] - s;
    #pragma unroll
    for (int j = 0; j < 8; ++j)
        if (base + j < n) out[base + j] = excl + pre[j];
    if (tid == 255) bsum[blockIdx.x] = ts[255];
}
__global__ __launch_bounds__(64) void scan2(int* __restrict__ bsum, int nb) {
    if (threadIdx.x == 0 && blockIdx.x == 0) {
        int run = 0;
        for (int i = 0; i < nb; ++i) { int t = bsum[i]; bsum[i] = run; run += t; }
    }
}
__global__ __launch_bounds__(256) void scan3(int* __restrict__ out,
    const int* __restrict__ bsum, int n, int total)
{
    int base = blockIdx.x * SCAN_TILE;
    int add = bsum[blockIdx.x];
    for (int j = threadIdx.x; j < SCAN_TILE; j += 256) {
        int k = base + j;
        if (k < n) out[k] += add;
    }
    if (blockIdx.x == 0 && threadIdx.x == 0) out[n] = total;
}
__global__ __launch_bounds__(256) void fill_csr(const int* __restrict__ src,
    const int* __restrict__ dst, int* __restrict__ cursor, int* __restrict__ col, int E)
{
    int e = blockIdx.x * 256 + threadIdx.x;
    if (e >= E) return;
    int pos = atomicAdd(&cursor[dst[e]], 1);
    col[pos] = src[e];
}

// ---------- vectorized projection: Y = X(NxK) @ W(KxH) + b, 8 nodes/block ----------
template<int K>
__global__ __launch_bounds__(256) void proj_kernel(const float* __restrict__ X,
    const float* __restrict__ W, const float* __restrict__ B,
    float* __restrict__ Y, int N)
{
    __shared__ float Wl[K][128];
    __shared__ float Bl[128];
    int tid = threadIdx.x;
    for (int i = tid; i < K * 128; i += 256) Wl[i >> 7][i & 127] = W[i];
    if (tid < 128) Bl[tid] = B[tid];
    __syncthreads();
    int ng = tid >> 5, lane = tid & 31;
    int n = blockIdx.x * 8 + ng;
    if (n >= N) return;
    const float* xr = X + (size_t)n * K;
    float xa[K];
    #pragma unroll
    for (int k4 = 0; k4 < K / 4; ++k4)
        *(float4*)&xa[k4 * 4] = *(const float4*)(xr + k4 * 4);
    int c0 = lane * 4;
    float4 acc = *(const float4*)&Bl[c0];
    #pragma unroll
    for (int k = 0; k < K; ++k) {
        float4 w = *(const float4*)&Wl[k][c0];
        acc.x += xa[k] * w.x; acc.y += xa[k] * w.y;
        acc.z += xa[k] * w.z; acc.w += xa[k] * w.w;
    }
    *(float4*)(Y + (size_t)n * H + c0) = acc;
}

// ---------- gather rows ----------
__global__ __launch_bounds__(256) void gather_rows(const float* __restrict__ src,
    const int* __restrict__ ids, float* __restrict__ dstp, int N)
{
    int t = blockIdx.x * 256 + threadIdx.x;
    if (t >= N * 32) return;
    int n = t >> 5, c4 = t & 31;
    int sid = ids[n];
    ((float4*)dstp)[(size_t)n * 32 + c4] = ((const float4*)src)[(size_t)sid * 32 + c4];
}

// ---------- combine stage 1 (parallel, 64 blocks) ----------
__global__ __launch_bounds__(256) void combine1_par(const float* __restrict__ kw,
    const float* __restrict__ kb, const float* __restrict__ vw, const float* __restrict__ vb,
    const float* __restrict__ a_rel, const float* __restrict__ m_rel,
    float* __restrict__ wkc, float* __restrict__ wc)
{
    __shared__ float Rs[64][132];
    int b = blockIdx.x;
    int combo = b >> 3;
    int pass  = (b >> 2) & 1;
    int slice = b & 3;
    int l = combo >> 2, r = combo & 3;
    const int src_t[4] = {1, 2, 0, 0};
    int st = src_t[r];
    const float* Ap = (pass ? vw : kw) + (size_t)(l*3 + st) * H * H;
    const float* Rp = (pass ? m_rel : a_rel) + (size_t)combo * H * H;
    float* Out = pass ? (wc + (size_t)combo * WC_STRIDE + 16384)
                      : (wkc + (size_t)combo * WKC_STRIDE);

    int tid = threadIdx.x;
    int i = slice * 32 + (tid >> 3);
    int jb = tid & 7;
    float acc[16];
    #pragma unroll
    for (int j = 0; j < 16; ++j) acc[j] = 0.f;

    for (int half = 0; half < 2; ++half) {
        __syncthreads();
        for (int idx = tid; idx < 64 * 128; idx += 256)
            Rs[idx >> 7][idx & 127] = Rp[(half * 64 + (idx >> 7)) * H + (idx & 127)];
        __syncthreads();
        for (int k = 0; k < 64; ++k) {
            float a = Ap[i * H + half * 64 + k];
            #pragma unroll
            for (int j = 0; j < 16; ++j) acc[j] += a * Rs[k][jb + j * 8];
        }
    }
    #pragma unroll
    for (int j = 0; j < 16; ++j) Out[i * H + jb + j * 8] = acc[j];

    // bvc = vb @ m_rel  (cvec/bkc terms cancel in segment softmax -> not computed)
    if (pass == 0 && slice == 0 && tid < 128) {
        const float* Avb = vb + (size_t)(l*3 + st) * H;
        const float* Rv = m_rel + (size_t)combo * H * H;
        float* bvc = wc + (size_t)combo * WC_STRIDE + 32896;
        float s = 0.f;
        for (int k = 0; k < H; ++k) s += Avb[k] * Rv[k * H + tid];
        bvc[tid] = s;
    }
}

// ---------- combine stage 2 (parallel, 32 blocks): QWc = qw[dt] @ WKc^T ----------
__global__ __launch_bounds__(256) void combine2_par(const float* __restrict__ qw,
    const float* __restrict__ qb, const float* __restrict__ wkc, float* __restrict__ wc)
{
    __shared__ float BsT[64][133];
    int b = blockIdx.x;
    int combo = b >> 2;
    int slice = b & 3;
    int l = combo >> 2, r = combo & 3;
    const int dst_t[4] = {0, 0, 1, 2};
    int dt = dst_t[r];
    const float* Q  = qw + (size_t)(l*3 + dt) * H * H;
    const float* Qb = qb + (size_t)(l*3 + dt) * H;
    const float* WKc = wkc + (size_t)combo * WKC_STRIDE;
    float* QWc = wc + (size_t)combo * WC_STRIDE;

    int tid = threadIdx.x;
    int i = slice * 32 + (tid >> 3);
    int jb = tid & 7;
    float acc[16];
    #pragma unroll
    for (int j = 0; j < 16; ++j) acc[j] = 0.f;

    for (int half = 0; half < 2; ++half) {
        __syncthreads();
        for (int idx = tid; idx < 64 * 128; idx += 256) {
            int j = idx >> 6, k = idx & 63;
            BsT[k][j] = WKc[j * H + half * 64 + k];
        }
        __syncthreads();
        for (int k = 0; k < 64; ++k) {
            float a = Q[i * H + half * 64 + k];
            #pragma unroll
            for (int j = 0; j < 16; ++j) acc[j] += a * BsT[k][jb + j * 8];
        }
    }
    #pragma unroll
    for (int j = 0; j < 16; ++j) QWc[i * H + jb + j * 8] = acc[j];

    if (slice == 0 && tid < 128) {
        float* qbc = wc + (size_t)combo * WC_STRIDE + 32768;
        float s = 0.f;
        for (int k = 0; k < H; ++k) s += Qb[k] * WKc[tid * H + k];
        qbc[tid] = s;
    }
}

// ---------- weight prep: transpose + split f32 -> bf16 hi/lo, layout [j][k] ----------
__global__ __launch_bounds__(256) void wprep(const float* __restrict__ wc,
    const float* __restrict__ aw, unsigned short* __restrict__ wt)
{
    int b = blockIdx.x;
    const float* src = (b < 16)
        ? wc + (size_t)(b >> 1) * WC_STRIDE + ((b & 1) ? 16384 : 0)
        : aw + (size_t)(b - 16) * 16384;
    unsigned short* hi = wt + (size_t)b * 32768;
    unsigned short* lo = hi + 16384;
    for (int idx = threadIdx.x; idx < 16384; idx += 256) {
        int k = idx >> 7, j = idx & 127;
        float w = src[idx];
        unsigned short h = f2bf(w);
        hi[j * 128 + k] = h;
        lo[j * 128 + k] = f2bf(w - bf2f(h));
    }
}

// ---------- 64-row tile GEMM machinery (32 KB LDS, XOR-swizzled, low-VGPR weights) ----------
#define STAGE_TILE(SRC, GELU)                                               \
    _Pragma("unroll")                                                       \
    for (int i = 0; i < 8; ++i) {                                           \
        int u = tid + i * 256;                                              \
        int n = u >> 5, c4 = u & 31;                                        \
        int gn = nb + n;                                                    \
        float4 v = make_float4(0.f, 0.f, 0.f, 0.f);                         \
        if (gn < N) v = *(const float4*)((SRC) + (size_t)gn * H + c4 * 4);  \
        if (GELU) {                                                         \
            v.x = gelu_exact(v.x); v.y = gelu_exact(v.y);                   \
            v.z = gelu_exact(v.z); v.w = gelu_exact(v.w);                   \
        }                                                                   \
        ushort4 h, lo;                                                      \
        h.x = f2bf(v.x); lo.x = f2bf(v.x - bf2f(h.x));                      \
        h.y = f2bf(v.y); lo.y = f2bf(v.y - bf2f(h.y));                      \
        h.z = f2bf(v.z); lo.z = f2bf(v.z - bf2f(h.z));                      \
        h.w = f2bf(v.w); lo.w = f2bf(v.w - bf2f(h.w));                      \
        int sc = (c4 * 4) ^ ((n & 7) << 3);                                 \
        *(ushort4*)&lds[0][n][sc] = h;                                      \
        *(ushort4*)&lds[1][n][sc] = lo;                                     \
    }

// weights loaded per-kb inside the loop: 4 live s8v instead of 16 (VGPR ~64)
#define MFMA_TILE64(WT)                                                     \
    _Pragma("unroll")                                                       \
    for (int kb = 0; kb < 4; ++kb) {                                        \
        const unsigned short* wp = (WT) + kb * 32 + kg * 8;                 \
        s8v bh0 = *(const s8v*)(wp + (size_t)(col0 + l15) * 128);           \
        s8v bh1 = *(const s8v*)(wp + (size_t)(col0 + 16 + l15) * 128);      \
        s8v bl0 = *(const s8v*)(wp + 16384 + (size_t)(col0 + l15) * 128);   \
        s8v bl1 = *(const s8v*)(wp + 16384 + (size_t)(col0 + 16 + l15) * 128); \
        _Pragma("unroll")                                                   \
        for (int m = 0; m < 4; ++m) {                                       \
            int row = m * 16 + l15;                                         \
            int offx = (kb * 32 + kg * 8) ^ ((row & 7) << 3);               \
            s8v ah = *(const s8v*)&lds[0][row][offx];                       \
            s8v al = *(const s8v*)&lds[1][row][offx];                       \
            acc[m][0] = __builtin_amdgcn_mfma_f32_16x16x32_bf16(ah, bh0, acc[m][0], 0, 0, 0); \
            acc[m][0] = __builtin_amdgcn_mfma_f32_16x16x32_bf16(al, bh0, acc[m][0], 0, 0, 0); \
            acc[m][0] = __builtin_amdgcn_mfma_f32_16x16x32_bf16(ah, bl0, acc[m][0], 0, 0, 0); \
            acc[m][1] = __builtin_amdgcn_mfma_f32_16x16x32_bf16(ah, bh1, acc[m][1], 0, 0, 0); \
            acc[m][1] = __builtin_amdgcn_mfma_f32_16x16x32_bf16(al, bh1, acc[m][1], 0, 0, 0); \
            acc[m][1] = __builtin_amdgcn_mfma_f32_16x16x32_bf16(ah, bl1, acc[m][1], 0, 0, 0); \
        }                                                                   \
    }

// ---------- MFMA split-bf16 GEMM (single weight set), 64 rows/block ----------
// MODE 0: Y = X@W + B
// MODE 1: Y = relu(beta*(gelu(X)@W + B) + (1-beta)*Xold)
// MODE 3: Y = X@W + gate*B    (gate = zb[n]>0; X==Y in-place allowed)
template<int MODE>
__global__ __launch_bounds__(256, 4) void mfma_gemm(const float* __restrict__ X,
    const unsigned short* __restrict__ Wt, const float* __restrict__ Bias,
    float* __restrict__ Y, int N, const float* __restrict__ Xold,
    const float* __restrict__ skipP, const float* __restrict__ zb)
{
    __shared__ unsigned short lds[2][64][128];
    int tid = threadIdx.x;
    int nb = blockIdx.x * 64;

    STAGE_TILE(X, MODE == 1)
    __syncthreads();

    int wid = tid >> 6, lane = tid & 63;
    int l15 = lane & 15, kg = lane >> 4;
    int col0 = wid * 32;

    f32x4 acc[4][2];
    #pragma unroll
    for (int m = 0; m < 4; ++m)
        #pragma unroll
        for (int n = 0; n < 2; ++n)
            acc[m][n] = (f32x4){0.f, 0.f, 0.f, 0.f};

    MFMA_TILE64(Wt)

    float beta = 0.f, omb = 0.f;
    if (MODE == 1) {
        float s = *skipP;
        beta = 1.f / (1.f + expf(-s));
        omb = 1.f - beta;
    }
    float bias0 = Bias[col0 + l15];
    float bias1 = Bias[col0 + 16 + l15];

    #pragma unroll
    for (int m = 0; m < 4; ++m) {
        #pragma unroll
        for (int r = 0; r < 4; ++r) {
            int grow = nb + m * 16 + kg * 4 + r;
            if (grow < N) {
                float gate = 1.f;
                if (MODE == 3) gate = (zb[grow] > 0.f) ? 1.f : 0.f;
                #pragma unroll
                for (int n = 0; n < 2; ++n) {
                    int col = col0 + n * 16 + l15;
                    float val = acc[m][n][r];
                    float bs = n ? bias1 : bias0;
                    size_t yi = (size_t)grow * H + col;
                    if (MODE == 0) {
                        Y[yi] = val + bs;
                    } else if (MODE == 3) {
                        Y[yi] = val + gate * bs;
                    } else {
                        float o = val + bs;
                        float xo = Xold[yi];
                        Y[yi] = fmaxf(beta * o + omb * xo, 0.f);
                    }
                }
            }
        }
    }
}

// ---------- fused dual qt GEMM: Y0 = X@W0 + b0, Y1 = X@W1 + b1 ----------
__global__ __launch_bounds__(256, 4) void mfma_gemm2q(const float* __restrict__ X,
    const unsigned short* __restrict__ Wt0, const unsigned short* __restrict__ Wt1,
    const float* __restrict__ b0, const float* __restrict__ b1,
    float* __restrict__ Y0, float* __restrict__ Y1, int N)
{
    __shared__ unsigned short lds[2][64][128];
    int tid = threadIdx.x;
    int nb = blockIdx.x * 64;

    STAGE_TILE(X, 0)
    __syncthreads();

    int wid = tid >> 6, lane = tid & 63;
    int l15 = lane & 15, kg = lane >> 4;
    int col0 = wid * 32;

    #pragma unroll
    for (int set = 0; set < 2; ++set) {
        const unsigned short* Wt = set ? Wt1 : Wt0;
        const float* Bias = set ? b1 : b0;
        float* Y = set ? Y1 : Y0;

        f32x4 acc[4][2];
        #pragma unroll
        for (int m = 0; m < 4; ++m)
            #pragma unroll
            for (int n = 0; n < 2; ++n)
                acc[m][n] = (f32x4){0.f, 0.f, 0.f, 0.f};

        MFMA_TILE64(Wt)

        float bias0 = Bias[col0 + l15];
        float bias1 = Bias[col0 + 16 + l15];
        #pragma unroll
        for (int m = 0; m < 4; ++m) {
            #pragma unroll
            for (int r = 0; r < 4; ++r) {
                int grow = nb + m * 16 + kg * 4 + r;
                if (grow < N) {
                    #pragma unroll
                    for (int n = 0; n < 2; ++n) {
                        int col = col0 + n * 16 + l15;
                        Y[(size_t)grow * H + col] = acc[m][n][r] + (n ? bias1 : bias0);
                    }
                }
            }
        }
    }
}

// ---------- fused K=256 V-GEMM: A0 <- A0@W0 + A1@W1 + gate0*b0 + gate1*b1 ----------
__global__ __launch_bounds__(256, 4) void mfma_gemmV2(float* __restrict__ A0,
    const float* __restrict__ A1,
    const unsigned short* __restrict__ Wt0, const unsigned short* __restrict__ Wt1,
    const float* __restrict__ bv0, const float* __restrict__ bv1,
    const float* __restrict__ z0, const float* __restrict__ z1, int N)
{
    __shared__ unsigned short lds[2][64][128];
    int tid = threadIdx.x;
    int nb = blockIdx.x * 64;
    int wid = tid >> 6, lane = tid & 63;
    int l15 = lane & 15, kg = lane >> 4;
    int col0 = wid * 32;

    f32x4 acc[4][2];
    #pragma unroll
    for (int m = 0; m < 4; ++m)
        #pragma unroll
        for (int n = 0; n < 2; ++n)
            acc[m][n] = (f32x4){0.f, 0.f, 0.f, 0.f};

    {
        STAGE_TILE(A0, 0)
        __syncthreads();
        MFMA_TILE64(Wt0)
    }
    __syncthreads();   // LDS reads done before restage
    {
        const float* A = A1;
        STAGE_TILE(A, 0)
        __syncthreads();
        MFMA_TILE64(Wt1)
    }

    float b00 = bv0[col0 + l15],  b01 = bv0[col0 + 16 + l15];
    float b10 = bv1[col0 + l15],  b11 = bv1[col0 + 16 + l15];

    #pragma unroll
    for (int m = 0; m < 4; ++m) {
        #pragma unroll
        for (int r = 0; r < 4; ++r) {
            int grow = nb + m * 16 + kg * 4 + r;
            if (grow < N) {
                float g0 = (z0[grow] > 0.f) ? 1.f : 0.f;
                float g1 = (z1[grow] > 0.f) ? 1.f : 0.f;
                #pragma unroll
                for (int n = 0; n < 2; ++n) {
                    int col = col0 + n * 16 + l15;
                    float bs = n ? (g0 * b01 + g1 * b11) : (g0 * b00 + g1 * b10);
                    A0[(size_t)grow * H + col] = acc[m][n][r] + bs;
                }
            }
        }
    }
}

// ---------- fused edge phase: per dst node, single pass over CSR ----------
__global__ __launch_bounds__(256) void gather_agg(const int* __restrict__ row_ptr,
    const int* __restrict__ col_idx, float* __restrict__ qtraw,
    const float* __restrict__ xsrc, const float* __restrict__ prel, int ridx,
    float* __restrict__ zout, int ndt)
{
    int g = blockIdx.x * 8 + (threadIdx.x >> 5);
    int lane = threadIdx.x & 31;
    if (g >= ndt) return;
    float4 qv = *(const float4*)(qtraw + (size_t)g * H + lane * 4);
    float scale = prel[ridx] * 0.08838834764831843f;   // 1/sqrt(128)
    int beg = row_ptr[g], end = row_ptr[g + 1];
    float4 acc = make_float4(0.f, 0.f, 0.f, 0.f);
    float z = 0.f;
    for (int i = beg; i < end; ++i) {
        int s = col_idx[i];
        float4 xv = *(const float4*)(xsrc + (size_t)s * H + lane * 4);
        float p = qv.x*xv.x + qv.y*xv.y + qv.z*xv.z + qv.w*xv.w;
        #pragma unroll
        for (int m = 16; m >= 1; m >>= 1) p += __shfl_xor(p, m);
        float ev = expf(p * scale);
        z += ev;
        acc.x += ev * xv.x; acc.y += ev * xv.y;
        acc.z += ev * xv.z; acc.w += ev * xv.w;
    }
    float inv = 1.f / (z + 1e-16f);
    float4 r = make_float4(acc.x * inv, acc.y * inv, acc.z * inv, acc.w * inv);
    *(float4*)(qtraw + (size_t)g * H + lane * 4) = r;
    if (lane == 0) zout[g] = z;
}

// ---------- output head ----------
__global__ __launch_bounds__(256) void out_kernel(const float* __restrict__ X,
    const float* __restrict__ Wo, const float* __restrict__ bo,
    float* __restrict__ out, int N)
{
    int t = blockIdx.x * 256 + threadIdx.x;
    int n = t >> 5, lane = t & 31;
    if (n >= N) return;
    float4 xv = *(const float4*)(X + (size_t)n * H + lane * 4);
    float xa[4]; *(float4*)xa = xv;
    float p0 = 0.f, p1 = 0.f;
    #pragma unroll
    for (int j = 0; j < 4; ++j) {
        p0 += xa[j] * Wo[(lane*4 + j)*2 + 0];
        p1 += xa[j] * Wo[(lane*4 + j)*2 + 1];
    }
    #pragma unroll
    for (int m = 16; m >= 1; m >>= 1) { p0 += __shfl_xor(p0, m); p1 += __shfl_xor(p1, m); }
    if (lane == 0) {
        out[(size_t)n*2 + 0] = p0 + bo[0];
        out[(size_t)n*2 + 1] = p1 + bo[1];
    }
}

extern "C" void kernel_launch(void* const* d_in, const int* in_sizes, int n_in,
                              void* d_out, int out_size, void* d_ws, size_t ws_size,
                              hipStream_t stream)
{
    const float* x_tx      = (const float*)d_in[0];
    const float* x_cust    = (const float*)d_in[1];
    const int*   merch_ids = (const int*)d_in[2];
    const int*   e_ct_src  = (const int*)d_in[3];
    const int*   e_ct_dst  = (const int*)d_in[4];
    const int*   e_mt_src  = (const int*)d_in[5];
    const int*   e_mt_dst  = (const int*)d_in[6];
    const float* proj_tx_w   = (const float*)d_in[7];
    const float* proj_tx_b   = (const float*)d_in[8];
    const float* proj_cust_w = (const float*)d_in[9];
    const float* proj_cust_b = (const float*)d_in[10];
    const float* merch_emb   = (const float*)d_in[11];
    const float* kw = (const float*)d_in[12];
    const float* kb = (const float*)d_in[13];
    const float* qw = (const float*)d_in[14];
    const float* qb = (const float*)d_in[15];
    const float* vw = (const float*)d_in[16];
    const float* vb = (const float*)d_in[17];
    const float* aw = (const float*)d_in[18];
    const float* ab = (const float*)d_in[19];
    const float* skip  = (const float*)d_in[20];
    const float* a_rel = (const float*)d_in[21];
    const float* m_rel = (const float*)d_in[22];
    const float* p_rel = (const float*)d_in[23];
    const float* out_w = (const float*)d_in[24];
    const float* out_b = (const float*)d_in[25];
    (void)in_sizes; (void)n_in;

    const size_t nsz[3] = {NTX, NCU, NME};

    // workspace layout — ~265 MB of 268.4 MB (256 MiB) budget
    float* ws = (float*)d_ws;
    size_t off = 0;
    float* xs[3];  for (int t = 0; t < 3; ++t) { xs[t] = ws + off; off += nsz[t]*H; }
    float* bufB    = ws + off; off += BUF_FLOATS;   // qt_r1/raw_r1; later agg1 @0, agg2 @AGG2_OFF
    float* edgebuf = ws + off; off += BUF_FLOATS;   // qt_r0/raw_r0 -> agg0 (in-place V2)
    float* zbuf0 = ws + off; off += NTX;
    float* zbuf1 = ws + off; off += NTX;
    float* wc   = ws + off; off += 8 * WC_STRIDE;
    float* wkc  = ws + off; off += 8 * WKC_STRIDE;
    int* ibase = (int*)(ws + off);
    const int rp_size[4] = {NTX + 1, NTX + 1, NCU + 1, NME + 1};
    int* rowp[4]; size_t ioff = 0;
    for (int r = 0; r < 4; ++r) { rowp[r] = ibase + ioff; ioff += rp_size[r]; }
    int* colix[4];
    for (int r = 0; r < 4; ++r) { colix[r] = ibase + ioff; ioff += NEDGE; }
    int* cursor = ibase + ioff; ioff += NTX;
    int* bsum   = ibase + ioff; ioff += 256;
    unsigned short* wt = (unsigned short*)(ibase + ioff);
    size_t needed_bytes = off * sizeof(float) + ioff * sizeof(int)
                        + (size_t)22 * 32768 * sizeof(unsigned short);

    if (ws_size < needed_bytes) {
        fill_val<<<(out_size + 255) / 256, 256, 0, stream>>>(
            (float*)d_out, out_size, (float)(ws_size >> 20));
        return;
    }

    const int src_t[4] = {1, 2, 0, 0};
    const int dst_t[4] = {0, 0, 1, 2};
    const int* esrc[4] = {e_ct_src, e_mt_src, e_ct_dst, e_mt_dst};
    const int* edst[4] = {e_ct_dst, e_mt_dst, e_ct_src, e_mt_src};

    // ---- build CSR per relation (edges constant across layers) ----
    const int egrid256 = (NEDGE + 255) / 256;
    for (int r = 0; r < 4; ++r) {
        int ndt = (int)nsz[dst_t[r]];
        int nb = (ndt + SCAN_TILE - 1) / SCAN_TILE;
        zero_int<<<(ndt + 255) / 256, 256, 0, stream>>>(cursor, ndt);
        count_deg<<<egrid256, 256, 0, stream>>>(edst[r], cursor, NEDGE);
        scan1<<<nb, 256, 0, stream>>>(cursor, rowp[r], bsum, ndt);
        scan2<<<1, 64, 0, stream>>>(bsum, nb);
        scan3<<<nb, 256, 0, stream>>>(rowp[r], bsum, ndt, NEDGE);
        copy_int<<<(ndt + 255) / 256, 256, 0, stream>>>(cursor, rowp[r], ndt);
        fill_csr<<<egrid256, 256, 0, stream>>>(esrc[r], edst[r], cursor, colix[r], NEDGE);
    }

    // precombine weights, then bf16 hi/lo transposed planes
    combine1_par<<<64, 256, 0, stream>>>(kw, kb, vw, vb, a_rel, m_rel, wkc, wc);
    combine2_par<<<32, 256, 0, stream>>>(qw, qb, wkc, wc);
    wprep<<<22, 256, 0, stream>>>(wc, aw, wt);

    // input projections
    proj_kernel<16><<<(NTX + 7) / 8, 256, 0, stream>>>(x_tx, proj_tx_w, proj_tx_b, xs[0], NTX);
    proj_kernel<32><<<(NCU + 7) / 8, 256, 0, stream>>>(x_cust, proj_cust_w, proj_cust_b, xs[1], NCU);
    gather_rows<<<(NME * 32 + 255) / 256, 256, 0, stream>>>(merch_emb, merch_ids, xs[2], NME);

    float* aggT[3] = { edgebuf, bufB, bufB + AGG2_OFF };

    for (int l = 0; l < NLAY; ++l) {
        int c0 = l * 4 + 0, c1 = l * 4 + 1;
        const float* W0 = wc + (size_t)c0 * WC_STRIDE;
        const float* W1 = wc + (size_t)c1 * WC_STRIDE;

        // fused r0+r1 qt (dt = tx for both): X read once
        mfma_gemm2q<<<(NTX + 63) / 64, 256, 0, stream>>>(
            xs[0], wt + (size_t)(c0*2) * 32768, wt + (size_t)(c1*2) * 32768,
            W0 + 32768, W1 + 32768, edgebuf, bufB, NTX);
        gather_agg<<<(NTX + 7) / 8, 256, 0, stream>>>(
            rowp[0], colix[0], edgebuf, xs[1], p_rel, c0, zbuf0, NTX);
        gather_agg<<<(NTX + 7) / 8, 256, 0, stream>>>(
            rowp[1], colix[1], bufB, xs[2], p_rel, c1, zbuf1, NTX);
        // agg0 = raw0@WV0 + raw1@WV1 (+ gated biases), in-place into edgebuf
        mfma_gemmV2<<<(NTX + 63) / 64, 256, 0, stream>>>(
            edgebuf, bufB, wt + (size_t)(c0*2 + 1) * 32768, wt + (size_t)(c1*2 + 1) * 32768,
            W0 + 32896, W1 + 32896, zbuf0, zbuf1, NTX);

        // r2 (dst=cust) and r3 (dst=merch): qt -> bufB regions, gather, V in-place
        for (int r = 2; r < 4; ++r) {
            int st = src_t[r], dt = dst_t[r];
            int ndt = (int)nsz[dt];
            int combo = l * 4 + r;
            const float* Wr = wc + (size_t)combo * WC_STRIDE;
            float* buf = aggT[dt];
            int grid = (ndt + 63) / 64;
            mfma_gemm<0><<<grid, 256, 0, stream>>>(
                xs[dt], wt + (size_t)(combo*2) * 32768, Wr + 32768, buf, ndt,
                nullptr, nullptr, nullptr);
            gather_agg<<<(ndt + 7) / 8, 256, 0, stream>>>(
                rowp[r], colix[r], buf, xs[st], p_rel, combo, zbuf0, ndt);
            mfma_gemm<3><<<grid, 256, 0, stream>>>(
                buf, wt + (size_t)(combo*2 + 1) * 32768, Wr + 32896, buf, ndt,
                nullptr, nullptr, zbuf0);
        }

        // update: xs = relu(beta*(gelu(agg)@aw + ab) + (1-beta)*xs)
        for (int t = 0; t < 3; ++t)
            mfma_gemm<1><<<(int)((nsz[t] + 63) / 64), 256, 0, stream>>>(
                aggT[t], wt + (size_t)(16 + l*3 + t) * 32768,
                ab + (size_t)(l*3 + t)*H, xs[t], (int)nsz[t],
                xs[t], skip + l*3 + t, nullptr);
    }

    out_kernel<<<(NTX * 32 + 255) / 256, 256, 0, stream>>>(xs[0], out_w, out_b, (float*)d_out, NTX);
}